// Round 20
// baseline (59.725 us; speedup 1.0000x reference)
//
#include <hip/hip_runtime.h>

#define LSEQ 1024
#define DH 64
#define NH 2

typedef __attribute__((ext_vector_type(8))) __bf16 bf16x8;
typedef __attribute__((ext_vector_type(4))) float f32x4;
typedef __attribute__((ext_vector_type(16))) float f32x16;
typedef __attribute__((ext_vector_type(4))) unsigned u32x4;
typedef __attribute__((ext_vector_type(8))) unsigned short ushort8;

__device__ __forceinline__ unsigned short f2bf(float f) {
  unsigned u = __float_as_uint(f);
  u += 0x7FFFu + ((u >> 16) & 1u);
  return (unsigned short)(u >> 16);
}
__device__ __forceinline__ unsigned cvt_pk_bf16(float lo, float hi) {
  unsigned r;
  asm("v_cvt_pk_bf16_f32 %0, %1, %2" : "=v"(r) : "v"(lo), "v"(hi));
  return r;
}
__device__ __forceinline__ void gload16(const void* g, void* l) {
  __builtin_amdgcn_global_load_lds(
      (const __attribute__((address_space(1))) void*)g,
      (__attribute__((address_space(3))) void*)l, 16, 0, 0);
}

// Q pre-scaled by log2(e)/sqrt(DH) at projection -> attn uses raw exp2.
#define QSCALE 0.1803368801111601f

// ---------------------------------------------------------------------------
// Stage 0: weights f32 -> bf16 + zero Vmean (blocks 0..47); zero the heavy
// half of out (rows >= 512, targets of split-K atomics) + lsumbuf
// (blocks 48..1071).
// ---------------------------------------------------------------------------
__global__ __launch_bounds__(256) void wconv_kernel(
    const float* __restrict__ Qw, const float* __restrict__ Kw,
    const float* __restrict__ Vw, unsigned short* __restrict__ Wbf,
    float* __restrict__ Vmean, float* __restrict__ out,
    float* __restrict__ lsumbuf)
{
  if (blockIdx.x < 48) {
    const int t = blockIdx.x * 256 + threadIdx.x;   // 0..12287
    if (t < NH * 32 * DH) Vmean[t] = 0.f;
    const int m = t >> 12;                          // matrix 0..2
    const float* W = (m == 0) ? Qw : (m == 1) ? Kw : Vw;
    const float4 v = ((const float4*)W)[t & 4095];
    uint2 u;
    u.x = cvt_pk_bf16(v.x, v.y);
    u.y = cvt_pk_bf16(v.z, v.w);
    *(uint2*)&Wbf[t * 4] = u;
  } else {
    const int gid = (blockIdx.x - 48) * 256 + threadIdx.x;  // 0..262143
    const float4 z = {0.f, 0.f, 0.f, 0.f};
    const int f4 = gid * 2;
    const int bb = f4 >> 14;                 // 16384 f4 per batch
    const int rem = f4 & 16383;
    float4* p = (float4*)(out + (size_t)bb * 131072 + 65536) + rem;
    p[0] = z; p[1] = z;
    if (gid < 8192) {
      float4* q = (float4*)lsumbuf + gid * 2;
      q[0] = z; q[1] = z;
    }
  }
}

// ---------------------------------------------------------------------------
// Stage 1: LOAD-BALANCED projection (r19, best measured).  768 identical
// single-matrix blocks; W staged in half-K pieces; 3 blocks/CU.
// ---------------------------------------------------------------------------
__global__ __launch_bounds__(256, 3) void proj_kernel(
    const float* __restrict__ queries, const float* __restrict__ keys,
    const unsigned short* __restrict__ Wbf,
    const float* __restrict__ Qb, const float* __restrict__ Kb,
    const float* __restrict__ Vb,
    unsigned short* __restrict__ Qbf, unsigned short* __restrict__ Kbf,
    unsigned short* __restrict__ Vt, float* __restrict__ Vmean)
{
  constexpr int LP = 136;
  __shared__ __align__(16) unsigned short Xs[128 * LP];   // 34816 B
  __shared__ __align__(16) unsigned short Wh[8192];       // 16384 B (half-K)

  const int t = threadIdx.x;
  const int lane = t & 63, w = t >> 6;
  const int c = lane & 15, g = lane >> 4;
  const int wrow = w * 32;

  const int mat = blockIdx.x >> 8;               // 0=Q, 1=K, 2=V
  const int rt  = (blockIdx.x & 255) * 128;
  const float* Xin = (mat == 0) ? queries : keys;
  const char* Wg = (const char*)(Wbf + mat * 16384);

#define WSTAGE_H(h) do {                                                   \
    _Pragma("unroll")                                                      \
    for (int i_ = 0; i_ < 4; ++i_) {                                       \
      const int off_ = t * 16 + i_ * 4096;       /* 0..16383 */            \
      const int lrow_ = off_ >> 7;               /* 0..127 */              \
      const int lch_ = (off_ >> 4) & 7;                                    \
      gload16(Wg + lrow_ * 256 + (h) * 128 + ((lch_ ^ (lrow_ & 7)) << 4),  \
              (char*)Wh + off_);                                           \
    }                                                                      \
  } while (0)

#define WFRAG_H(ct_, j_) \
  (*(const bf16x8*)&Wh[((ct_) * 16 + c) * 64 + (((j_) ^ (c & 7)) << 3)])

#define XFRAG(half_, kc_) \
  (*(const bf16x8*)&Xs[(wrow + (half_) * 16 + c) * LP + (kc_) * 32 + g * 8])

  WSTAGE_H(0);

  const float4* X4 = (const float4*)(Xin + (size_t)rt * 128);
#pragma unroll
  for (int i = 0; i < 16; ++i) {
    const int e4 = t + i * 256;
    const float4 v = X4[e4];
    const int e = e4 * 4;
    uint2 u;
    u.x = cvt_pk_bf16(v.x, v.y);
    u.y = cvt_pk_bf16(v.z, v.w);
    *(uint2*)&Xs[(e >> 7) * LP + (e & 127)] = u;
  }
  __syncthreads();   // drains gload16 (vmcnt) + X ds_writes

  f32x4 acc[2][8];
#pragma unroll
  for (int i = 0; i < 2; ++i)
#pragma unroll
    for (int j = 0; j < 8; ++j) acc[i][j] = (f32x4){0.f, 0.f, 0.f, 0.f};

#pragma unroll
  for (int kc2 = 0; kc2 < 2; ++kc2) {
    const bf16x8 a0 = XFRAG(0, kc2);
    const bf16x8 a1 = XFRAG(1, kc2);
#pragma unroll
    for (int ct = 0; ct < 8; ++ct) {
      const bf16x8 bfr = WFRAG_H(ct, kc2 * 4 + g);
      acc[0][ct] = __builtin_amdgcn_mfma_f32_16x16x32_bf16(a0, bfr, acc[0][ct], 0, 0, 0);
      acc[1][ct] = __builtin_amdgcn_mfma_f32_16x16x32_bf16(a1, bfr, acc[1][ct], 0, 0, 0);
    }
  }
  __syncthreads();   // all waves done reading Wh half-0
  WSTAGE_H(1);
  __syncthreads();   // half-1 staged

#pragma unroll
  for (int kc2 = 0; kc2 < 2; ++kc2) {
    const bf16x8 a0 = XFRAG(0, kc2 + 2);
    const bf16x8 a1 = XFRAG(1, kc2 + 2);
#pragma unroll
    for (int ct = 0; ct < 8; ++ct) {
      const bf16x8 bfr = WFRAG_H(ct, kc2 * 4 + g);
      acc[0][ct] = __builtin_amdgcn_mfma_f32_16x16x32_bf16(a0, bfr, acc[0][ct], 0, 0, 0);
      acc[1][ct] = __builtin_amdgcn_mfma_f32_16x16x32_bf16(a1, bfr, acc[1][ct], 0, 0, 0);
    }
  }

  if (mat == 2) {
#pragma unroll
    for (int ct = 0; ct < 8; ++ct) {
      const float bv = Vb[ct * 16 + c];
      float cs = 8.f * bv;
#pragma unroll
      for (int qf = 0; qf < 2; ++qf)
#pragma unroll
        for (int r = 0; r < 4; ++r) cs += acc[qf][ct][r];
      cs += __shfl_xor(cs, 16);
      cs += __shfl_xor(cs, 32);
      if (g == 0) {
        const int col = ct * 16 + c;
        const int bh = (rt >> 10) * NH + (col >> 6);
        atomicAdd(&Vmean[bh * DH + (col & 63)], cs);
      }
    }
    __syncthreads();
#pragma unroll
    for (int qf = 0; qf < 2; ++qf)
#pragma unroll
      for (int ct = 0; ct < 8; ++ct) {
        const float bv = Vb[ct * 16 + c];
        const int col = ct * 16 + c;
        uint2 u;
        u.x = cvt_pk_bf16(acc[qf][ct][0] + bv, acc[qf][ct][1] + bv);
        u.y = cvt_pk_bf16(acc[qf][ct][2] + bv, acc[qf][ct][3] + bv);
        *(uint2*)&Xs[col * LP + wrow + qf * 16 + g * 4] = u;
      }
    __syncthreads();
    const int b = rt >> 10, l0 = rt & 1023;
#pragma unroll
    for (int i = 0; i < 8; ++i) {
      const int e = i * 2048 + t * 8;
      const int col = e >> 7, li = e & 127;
      const ushort8 v8 = *(const ushort8*)&Xs[col * LP + li];
      const int hh = col >> 6, dh = col & 63;
      unsigned short* vp = Vt + ((size_t)(b * NH + hh)) * (DH * LSEQ) +
                           (size_t)dh * LSEQ + l0 + li;
      *(ushort8*)vp = v8;
    }
  } else {
    const float* biasA = mat ? Kb : Qb;
    const float qs = mat ? 1.0f : QSCALE;
    __syncthreads();
#pragma unroll
    for (int qf = 0; qf < 2; ++qf)
#pragma unroll
      for (int ct = 0; ct < 8; ++ct) {
        const float bv = biasA[ct * 16 + c];
#pragma unroll
        for (int r = 0; r < 4; ++r)
          Xs[(wrow + qf * 16 + g * 4 + r) * LP + ct * 16 + c] =
              f2bf((acc[qf][ct][r] + bv) * qs);
      }
    __syncthreads();
    unsigned short* outp = (mat ? Kbf : Qbf) + (size_t)rt * 128;
#pragma unroll
    for (int i = 0; i < 8; ++i) {
      const int e = i * 2048 + t * 8;
      *(ushort8*)&outp[e] = *(const ushort8*)&Xs[(e >> 7) * LP + (e & 127)];
    }
  }
#undef WSTAGE_H
#undef WFRAG_H
#undef XFRAG
}

// ---------------------------------------------------------------------------
// Stage 2: SPLIT-K causal attention (makespan balance, the r19 lesson).
// Old: blocks had 1..16 KV iters; 16-iter blocks set the makespan while
// light blocks idled.  Fixed-max softmax makes partials trivially additive,
// so heavy tiles (qt>=8, rows>=512) are split:
//   A-unit (ucode 8..15): KV [0,8) of qt=ucode -- 8 iters, no masking.
//   Combined (ucode 0..7): KV [8,qt] of qt=8+u (diag masked), THEN full
//     light tile j=7-u -- (u+1)+(8-u)=9 iters.
// Heavy partials: f32 atomicAdd into pre-zeroed out + lsumbuf (two-term
// atomic add is commutative -> deterministic).  Light tiles: direct
// epilogue.  64bh x 16 units = 1024 blocks, ALL 8-9 iters, 4/CU.
// Per-tile math identical to r12 (32x32x16 MFMA, in-register P, acc5).
// ---------------------------------------------------------------------------
__global__ __launch_bounds__(128, 2) void attn_kernel(
    const unsigned short* __restrict__ Qbf, const unsigned short* __restrict__ Kbf,
    const unsigned short* __restrict__ Vt, const float* __restrict__ Vmean,
    const int* __restrict__ time_mask, float* __restrict__ out,
    float* __restrict__ lsumbuf)
{
  __shared__ __align__(16) char smem[33280];  // K dbuf 16K | V dbuf 16K | tmx

  const int tid = threadIdx.x;
  const int lane = tid & 63, w = tid >> 6;    // w in {0,1}
  const int lq = lane & 31, hi = lane >> 5;
  const int s7 = lq & 7;

  const int wgid = blockIdx.x;
  const int xcd = wgid & 7;
  const int idx = wgid >> 3;                  // 0..127
  const int bh  = xcd * 8 + (idx & 7);        // 8 bh per XCD
  const int ucode = idx >> 3;                 // 0..15 (combined units first)
  const int b = bh >> 1, h = bh & 1;

  const unsigned short* Qp = Qbf + ((size_t)b * LSEQ) * 128 + h * 64;
  const char* Kpb = (const char*)(Kbf + ((size_t)b * LSEQ) * 128 + h * 64);
  const char* Vpb = (const char*)(Vt + (size_t)bh * (DH * LSEQ));

  const int comb = (ucode < 8);
  int qbase, tkb, tke, tdiag, part;
  const int nphase = comb ? 2 : 1;
  if (comb) {
    const int qt = 8 + ucode;
    qbase = qt * 64; tkb = 8; tke = qt; tdiag = qt; part = 1;
  } else {
    qbase = ucode * 64; tkb = 0; tke = 7; tdiag = -1; part = 1;
  }

#define STAGE(tkv, bi) do {                                                   \
    const int kv_ = (tkv) * 64;                                               \
    _Pragma("unroll")                                                         \
    for (int r_ = 0; r_ < 4; ++r_) {                                          \
      const int off_ = tid * 16 + r_ * 2048;                                  \
      const int row_ = off_ >> 7;                                             \
      const int chk_ = (((off_ >> 4) & 7) ^ (row_ & 7)) << 4;                 \
      gload16(Kpb + (size_t)(kv_ + row_) * 256 + chk_,                        \
              (char*)smem + (bi) * 8192 + r_ * 2048 + tid * 16);              \
      gload16(Vpb + (size_t)row_ * 2048 + kv_ * 2 + chk_,                     \
              (char*)smem + 16384 + (bi) * 8192 + r_ * 2048 + tid * 16);      \
    }                                                                         \
  } while (0)

#define PLSWAP(x_, y_) asm("v_permlane32_swap_b32 %0, %1" : "+v"(x_), "+v"(y_))

#define MKPA(pk_, m_, dst_) do {                                              \
    unsigned x0_ = pk_[4*(m_)], x1_ = pk_[4*(m_)+1];                          \
    unsigned y0_ = pk_[4*(m_)+2], y1_ = pk_[4*(m_)+3];                        \
    PLSWAP(x0_, y0_); PLSWAP(x1_, y1_);                                       \
    u32x4 u_ = {x0_, x1_, y0_, y1_};                                          \
    dst_ = *(bf16x8*)&u_;                                                     \
  } while (0)

  const __bf16 one = (__bf16)1.0f;
  const bf16x8 vones = {one, one, one, one, one, one, one, one};

  for (int ph = 0; ph < nphase; ++ph) {
    if (ph == 1) {   // light tile of a combined unit
      const int j = 7 - ucode;
      qbase = j * 64; tkb = 0; tke = j; tdiag = j; part = 0;
    }

    bf16x8 qa[4];
#pragma unroll
    for (int kc4 = 0; kc4 < 4; ++kc4)
      qa[kc4] = *(const bf16x8*)&Qp[(qbase + w * 32 + lq) * 128 + kc4 * 16 + hi * 8];

    f32x16 acc0 = {}, acc1 = {}, acc5 = {};

    STAGE(tkb, tkb & 1);
    __syncthreads();

    for (int tk = tkb; tk <= tke; ++tk) {
      const int cur = tk & 1;
      if (tk < tke) STAGE(tk + 1, cur ^ 1);

      const char* Kl = smem + cur * 8192;
      const char* Vl = smem + 16384 + cur * 8192;

      f32x16 s0 = {}, s1 = {};
      __builtin_amdgcn_s_setprio(1);
#pragma unroll
      for (int kc4 = 0; kc4 < 4; ++kc4) {
        const bf16x8 kf = *(const bf16x8*)(Kl + (lq << 7) + (((2 * kc4 + hi) ^ s7) << 4));
        s0 = __builtin_amdgcn_mfma_f32_32x32x16_bf16(kf, qa[kc4], s0, 0, 0, 0);
      }
#pragma unroll
      for (int kc4 = 0; kc4 < 4; ++kc4) {
        const bf16x8 kf = *(const bf16x8*)(Kl + ((32 + lq) << 7) + (((2 * kc4 + hi) ^ s7) << 4));
        s1 = __builtin_amdgcn_mfma_f32_32x32x16_bf16(kf, qa[kc4], s1, 0, 0, 0);
      }
      __builtin_amdgcn_s_setprio(0);

      bf16x8 vf[4][2];
#pragma unroll
      for (int kc4 = 0; kc4 < 4; ++kc4)
#pragma unroll
        for (int dt = 0; dt < 2; ++dt)
          vf[kc4][dt] = *(const bf16x8*)(Vl + ((dt * 32 + lq) << 7) + (((2 * kc4 + hi) ^ s7) << 4));

      const bool diag = (tk == tdiag);
      const int kv = tk * 64;
      const int qrow = qbase + w * 32 + lq;
      float p0[16], p1[16];
#pragma unroll
      for (int r = 0; r < 16; ++r) {
        const int krow = (r & 3) + 8 * (r >> 2) + 4 * hi;
        float e0 = __builtin_amdgcn_exp2f(s0[r]);
        float e1 = __builtin_amdgcn_exp2f(s1[r]);
        if (diag) {
          if (kv + krow > qrow)      e0 = 0.f;
          if (kv + 32 + krow > qrow) e1 = 0.f;
        }
        p0[r] = e0; p1[r] = e1;
      }

      unsigned pk0[8], pk1[8];
#pragma unroll
      for (int bb = 0; bb < 4; ++bb) {
        pk0[2*bb]   = cvt_pk_bf16(p0[4*bb],   p0[4*bb+1]);
        pk0[2*bb+1] = cvt_pk_bf16(p0[4*bb+2], p0[4*bb+3]);
        pk1[2*bb]   = cvt_pk_bf16(p1[4*bb],   p1[4*bb+1]);
        pk1[2*bb+1] = cvt_pk_bf16(p1[4*bb+2], p1[4*bb+3]);
      }

      bf16x8 pa;
      __builtin_amdgcn_s_setprio(1);
      MKPA(pk0, 0, pa);
      acc0 = __builtin_amdgcn_mfma_f32_32x32x16_bf16(pa, vf[0][0], acc0, 0, 0, 0);
      acc1 = __builtin_amdgcn_mfma_f32_32x32x16_bf16(pa, vf[0][1], acc1, 0, 0, 0);
      acc5 = __builtin_amdgcn_mfma_f32_32x32x16_bf16(pa, vones,    acc5, 0, 0, 0);
      MKPA(pk0, 1, pa);
      acc0 = __builtin_amdgcn_mfma_f32_32x32x16_bf16(pa, vf[1][0], acc0, 0, 0, 0);
      acc1 = __builtin_amdgcn_mfma_f32_32x32x16_bf16(pa, vf[1][1], acc1, 0, 0, 0);
      acc5 = __builtin_amdgcn_mfma_f32_32x32x16_bf16(pa, vones,    acc5, 0, 0, 0);
      MKPA(pk1, 0, pa);
      acc0 = __builtin_amdgcn_mfma_f32_32x32x16_bf16(pa, vf[2][0], acc0, 0, 0, 0);
      acc1 = __builtin_amdgcn_mfma_f32_32x32x16_bf16(pa, vf[2][1], acc1, 0, 0, 0);
      acc5 = __builtin_amdgcn_mfma_f32_32x32x16_bf16(pa, vones,    acc5, 0, 0, 0);
      MKPA(pk1, 1, pa);
      acc0 = __builtin_amdgcn_mfma_f32_32x32x16_bf16(pa, vf[3][0], acc0, 0, 0, 0);
      acc1 = __builtin_amdgcn_mfma_f32_32x32x16_bf16(pa, vf[3][1], acc1, 0, 0, 0);
      acc5 = __builtin_amdgcn_mfma_f32_32x32x16_bf16(pa, vones,    acc5, 0, 0, 0);
      __builtin_amdgcn_s_setprio(0);

      __syncthreads();
    }

    if (part) {
      // heavy-tile partial: atomic accumulate (rows pre-zeroed; exactly two
      // contributors per address; two-term f32 add is commutative).
#pragma unroll
      for (int r = 0; r < 16; ++r) {
        const int qr = (r & 3) + 8 * (r >> 2) + 4 * hi;
        const int grow = qbase + w * 32 + qr;
        float* orow = out + (size_t)(b * LSEQ + grow) * (NH * DH) + h * DH;
        atomicAdd(&orow[lq], acc0[r]);
        atomicAdd(&orow[32 + lq], acc1[r]);
        if (lq == 0) atomicAdd(&lsumbuf[bh * LSEQ + grow], acc5[r]);
      }
    } else {
      // light-tile direct epilogue
      int* tmx = (int*)(smem + 32768 + w * 128);
      if (hi == 0)
        tmx[lq] = time_mask[b * LSEQ + qbase + w * 32 + lq];
      asm volatile("s_waitcnt lgkmcnt(0)" ::: "memory");
      __builtin_amdgcn_sched_barrier(0);

      const float vmv0 = Vmean[bh * DH + lq]      * (1.0f / 1024.0f);
      const float vmv1 = Vmean[bh * DH + 32 + lq] * (1.0f / 1024.0f);
#pragma unroll
      for (int r = 0; r < 16; ++r) {
        const int qr = (r & 3) + 8 * (r >> 2) + 4 * hi;
        const int tm = tmx[qr];
        const float wv = 1.0f / acc5[r];
        float* orow = out + (size_t)(b * LSEQ + qbase + w * 32 + qr) * (NH * DH) + h * DH;
        orow[lq]      = tm ? vmv0 : acc0[r] * wv;
        orow[32 + lq] = tm ? vmv1 : acc1[r] * wv;
      }
    }
  }
#undef STAGE
#undef PLSWAP
#undef MKPA
}

// ---------------------------------------------------------------------------
// Stage 3: normalize split-K rows (>=512): out = tm ? Vmean/1024 : acc/lsum.
// ---------------------------------------------------------------------------
__global__ __launch_bounds__(256) void norm_kernel(
    float* __restrict__ out, const float* __restrict__ lsumbuf,
    const float* __restrict__ Vmean, const int* __restrict__ time_mask)
{
  const int gid = blockIdx.x * 256 + threadIdx.x;   // 0..262143
  const int col8 = gid & 15;
  const int rb = gid >> 4;                          // 0..16383
  const int b = rb >> 9;
  const int row = 512 + (rb & 511);
  const int col = col8 * 8;
  const int h = col >> 6;
  const int bh = b * NH + h;
  const int tm = time_mask[b * LSEQ + row];
  float* p = out + (size_t)(b * LSEQ + row) * (NH * DH) + col;
  if (tm) {
    const float* vm = Vmean + bh * DH + (col & 63);
    float4 o0, o1;
    o0.x = vm[0] * (1.0f/1024.0f); o0.y = vm[1] * (1.0f/1024.0f);
    o0.z = vm[2] * (1.0f/1024.0f); o0.w = vm[3] * (1.0f/1024.0f);
    o1.x = vm[4] * (1.0f/1024.0f); o1.y = vm[5] * (1.0f/1024.0f);
    o1.z = vm[6] * (1.0f/1024.0f); o1.w = vm[7] * (1.0f/1024.0f);
    *(float4*)p = o0; *(float4*)(p + 4) = o1;
  } else {
    const float inv = 1.0f / lsumbuf[bh * LSEQ + row];
    float4 a = *(float4*)p, c = *(float4*)(p + 4);
    a.x *= inv; a.y *= inv; a.z *= inv; a.w *= inv;
    c.x *= inv; c.y *= inv; c.z *= inv; c.w *= inv;
    *(float4*)p = a; *(float4*)(p + 4) = c;
  }
}

// ---------------------------------------------------------------------------
extern "C" void kernel_launch(void* const* d_in, const int* in_sizes, int n_in,
                              void* d_out, int out_size, void* d_ws, size_t ws_size,
                              hipStream_t stream) {
  const float* queries   = (const float*)d_in[0];
  const float* keys      = (const float*)d_in[1];
  const int*   time_mask = (const int*)d_in[2];
  // d_in[3] = attn_mask: deterministically triu(k=1); computed from indices.
  const float* Qw = (const float*)d_in[4];
  const float* Qb = (const float*)d_in[5];
  const float* Kw = (const float*)d_in[6];
  const float* Kb = (const float*)d_in[7];
  const float* Vw = (const float*)d_in[8];
  const float* Vb = (const float*)d_in[9];
  float* out = (float*)d_out;

  char* ws = (char*)d_ws;
  unsigned short* Wbf    = (unsigned short*)(ws);                     //  98,304 B
  float*          Vmean  = (float*)(ws + 98304);                      //  16,384 B
  unsigned short* Qbf    = (unsigned short*)(ws + 114688);            // 8,388,608
  unsigned short* Kbf    = (unsigned short*)(ws + 8503296);           // 8,388,608
  unsigned short* Vtp    = (unsigned short*)(ws + 16891904);          // 8,388,608
  float*          lsumbf = (float*)(ws + 25280512);                   //   262,144

  wconv_kernel<<<1072, 256, 0, stream>>>(Qw, Kw, Vw, Wbf, Vmean, out, lsumbf);
  proj_kernel<<<768, 256, 0, stream>>>(queries, keys, Wbf, Qb, Kb, Vb,
                                       Qbf, Kbf, Vtp, Vmean);
  attn_kernel<<<1024, 128, 0, stream>>>(Qbf, Kbf, Vtp, Vmean, time_mask, out,
                                        lsumbf);
  norm_kernel<<<1024, 256, 0, stream>>>(out, lsumbf, Vmean, time_mask);
}

// Round 21
// 46.254 us; speedup vs baseline: 1.2912x; 1.2912x over previous
//
#include <hip/hip_runtime.h>

#define LSEQ 1024
#define DH 64
#define NH 2

typedef __attribute__((ext_vector_type(8))) __bf16 bf16x8;
typedef __attribute__((ext_vector_type(4))) float f32x4;
typedef __attribute__((ext_vector_type(16))) float f32x16;
typedef __attribute__((ext_vector_type(4))) unsigned u32x4;
typedef __attribute__((ext_vector_type(8))) unsigned short ushort8;

__device__ __forceinline__ unsigned short f2bf(float f) {
  unsigned u = __float_as_uint(f);
  u += 0x7FFFu + ((u >> 16) & 1u);
  return (unsigned short)(u >> 16);
}
__device__ __forceinline__ unsigned cvt_pk_bf16(float lo, float hi) {
  unsigned r;
  asm("v_cvt_pk_bf16_f32 %0, %1, %2" : "=v"(r) : "v"(lo), "v"(hi));
  return r;
}
__device__ __forceinline__ void gload16(const void* g, void* l) {
  __builtin_amdgcn_global_load_lds(
      (const __attribute__((address_space(1))) void*)g,
      (__attribute__((address_space(3))) void*)l, 16, 0, 0);
}

// Q pre-scaled by log2(e)/sqrt(DH) at projection -> attn uses raw exp2.
#define QSCALE 0.1803368801111601f

// ---------------------------------------------------------------------------
// Stage 0: weights f32 -> bf16 (3 x 128x128) + zero Vmean.  48 blocks.
// ---------------------------------------------------------------------------
__global__ __launch_bounds__(256) void wconv_kernel(
    const float* __restrict__ Qw, const float* __restrict__ Kw,
    const float* __restrict__ Vw, unsigned short* __restrict__ Wbf,
    float* __restrict__ Vmean)
{
  const int t = blockIdx.x * 256 + threadIdx.x;   // 0..12287
  if (t < NH * 32 * DH) Vmean[t] = 0.f;
  const int m = t >> 12;                          // matrix 0..2
  const float* W = (m == 0) ? Qw : (m == 1) ? Kw : Vw;
  const float4 v = ((const float4*)W)[t & 4095];
  uint2 u;
  u.x = cvt_pk_bf16(v.x, v.y);
  u.y = cvt_pk_bf16(v.z, v.w);
  *(uint2*)&Wbf[t * 4] = u;
}

// ---------------------------------------------------------------------------
// Stage 1: LOAD-BALANCED projection (r19, best measured).  768 identical
// single-matrix blocks (mat = bid/256: Q/K/V x 256 row-tiles of 128) --
// fixes the 2:1 heavy/light block imbalance.  W staged in HALF-K pieces
// (16KB buffer): stage k[0,64) -> MFMA kc0-1 -> barrier -> stage k[64,128)
// -> MFMA kc2-3.  LDS = 34.8 + 16.4 = 51.2KB -> 3 blocks/CU.
// ---------------------------------------------------------------------------
__global__ __launch_bounds__(256, 3) void proj_kernel(
    const float* __restrict__ queries, const float* __restrict__ keys,
    const unsigned short* __restrict__ Wbf,
    const float* __restrict__ Qb, const float* __restrict__ Kb,
    const float* __restrict__ Vb,
    unsigned short* __restrict__ Qbf, unsigned short* __restrict__ Kbf,
    unsigned short* __restrict__ Vt, float* __restrict__ Vmean)
{
  constexpr int LP = 136;
  __shared__ __align__(16) unsigned short Xs[128 * LP];   // 34816 B
  __shared__ __align__(16) unsigned short Wh[8192];       // 16384 B (half-K)

  const int t = threadIdx.x;
  const int lane = t & 63, w = t >> 6;
  const int c = lane & 15, g = lane >> 4;
  const int wrow = w * 32;

  const int mat = blockIdx.x >> 8;               // 0=Q, 1=K, 2=V
  const int rt  = (blockIdx.x & 255) * 128;
  const float* Xin = (mat == 0) ? queries : keys;
  const char* Wg = (const char*)(Wbf + mat * 16384);

#define WSTAGE_H(h) do {                                                   \
    _Pragma("unroll")                                                      \
    for (int i_ = 0; i_ < 4; ++i_) {                                       \
      const int off_ = t * 16 + i_ * 4096;       /* 0..16383 */            \
      const int lrow_ = off_ >> 7;               /* 0..127 */              \
      const int lch_ = (off_ >> 4) & 7;                                    \
      gload16(Wg + lrow_ * 256 + (h) * 128 + ((lch_ ^ (lrow_ & 7)) << 4),  \
              (char*)Wh + off_);                                           \
    }                                                                      \
  } while (0)

#define WFRAG_H(ct_, j_) \
  (*(const bf16x8*)&Wh[((ct_) * 16 + c) * 64 + (((j_) ^ (c & 7)) << 3)])

#define XFRAG(half_, kc_) \
  (*(const bf16x8*)&Xs[(wrow + (half_) * 16 + c) * LP + (kc_) * 32 + g * 8])

  WSTAGE_H(0);

  // stage X tile (128x128 f32 -> bf16 LDS)
  const float4* X4 = (const float4*)(Xin + (size_t)rt * 128);
#pragma unroll
  for (int i = 0; i < 16; ++i) {
    const int e4 = t + i * 256;
    const float4 v = X4[e4];
    const int e = e4 * 4;
    uint2 u;
    u.x = cvt_pk_bf16(v.x, v.y);
    u.y = cvt_pk_bf16(v.z, v.w);
    *(uint2*)&Xs[(e >> 7) * LP + (e & 127)] = u;
  }
  __syncthreads();   // drains gload16 (vmcnt) + X ds_writes

  f32x4 acc[2][8];
#pragma unroll
  for (int i = 0; i < 2; ++i)
#pragma unroll
    for (int j = 0; j < 8; ++j) acc[i][j] = (f32x4){0.f, 0.f, 0.f, 0.f};

  // ---- half 0: kc = 0,1 ----
#pragma unroll
  for (int kc2 = 0; kc2 < 2; ++kc2) {
    const bf16x8 a0 = XFRAG(0, kc2);
    const bf16x8 a1 = XFRAG(1, kc2);
#pragma unroll
    for (int ct = 0; ct < 8; ++ct) {
      const bf16x8 bfr = WFRAG_H(ct, kc2 * 4 + g);
      acc[0][ct] = __builtin_amdgcn_mfma_f32_16x16x32_bf16(a0, bfr, acc[0][ct], 0, 0, 0);
      acc[1][ct] = __builtin_amdgcn_mfma_f32_16x16x32_bf16(a1, bfr, acc[1][ct], 0, 0, 0);
    }
  }
  __syncthreads();   // all waves done reading Wh half-0
  WSTAGE_H(1);
  __syncthreads();   // half-1 staged

  // ---- half 1: kc = 2,3 ----
#pragma unroll
  for (int kc2 = 0; kc2 < 2; ++kc2) {
    const bf16x8 a0 = XFRAG(0, kc2 + 2);
    const bf16x8 a1 = XFRAG(1, kc2 + 2);
#pragma unroll
    for (int ct = 0; ct < 8; ++ct) {
      const bf16x8 bfr = WFRAG_H(ct, kc2 * 4 + g);
      acc[0][ct] = __builtin_amdgcn_mfma_f32_16x16x32_bf16(a0, bfr, acc[0][ct], 0, 0, 0);
      acc[1][ct] = __builtin_amdgcn_mfma_f32_16x16x32_bf16(a1, bfr, acc[1][ct], 0, 0, 0);
    }
  }

  if (mat == 2) {
    // Vmean partial column sums (32 rows per wave)
#pragma unroll
    for (int ct = 0; ct < 8; ++ct) {
      const float bv = Vb[ct * 16 + c];
      float cs = 8.f * bv;
#pragma unroll
      for (int qf = 0; qf < 2; ++qf)
#pragma unroll
        for (int r = 0; r < 4; ++r) cs += acc[qf][ct][r];
      cs += __shfl_xor(cs, 16);
      cs += __shfl_xor(cs, 32);
      if (g == 0) {
        const int col = ct * 16 + c;
        const int bh = (rt >> 10) * NH + (col >> 6);
        atomicAdd(&Vmean[bh * DH + (col & 63)], cs);
      }
    }
    // V epilogue: transpose-pack into Xs, then [bh][d][l] global write
    __syncthreads();   // all XFRAG reads done
#pragma unroll
    for (int qf = 0; qf < 2; ++qf)
#pragma unroll
      for (int ct = 0; ct < 8; ++ct) {
        const float bv = Vb[ct * 16 + c];
        const int col = ct * 16 + c;
        uint2 u;
        u.x = cvt_pk_bf16(acc[qf][ct][0] + bv, acc[qf][ct][1] + bv);
        u.y = cvt_pk_bf16(acc[qf][ct][2] + bv, acc[qf][ct][3] + bv);
        *(uint2*)&Xs[col * LP + wrow + qf * 16 + g * 4] = u;
      }
    __syncthreads();
    const int b = rt >> 10, l0 = rt & 1023;
#pragma unroll
    for (int i = 0; i < 8; ++i) {
      const int e = i * 2048 + t * 8;
      const int col = e >> 7, li = e & 127;
      const ushort8 v8 = *(const ushort8*)&Xs[col * LP + li];
      const int hh = col >> 6, dh = col & 63;
      unsigned short* vp = Vt + ((size_t)(b * NH + hh)) * (DH * LSEQ) +
                           (size_t)dh * LSEQ + l0 + li;
      *(ushort8*)vp = v8;
    }
  } else {
    // Q/K epilogue: row-major pack (+bias, Q pre-scaled), coalesced write
    const float* biasA = mat ? Kb : Qb;
    const float qs = mat ? 1.0f : QSCALE;
    __syncthreads();   // all XFRAG reads done
#pragma unroll
    for (int qf = 0; qf < 2; ++qf)
#pragma unroll
      for (int ct = 0; ct < 8; ++ct) {
        const float bv = biasA[ct * 16 + c];
#pragma unroll
        for (int r = 0; r < 4; ++r)
          Xs[(wrow + qf * 16 + g * 4 + r) * LP + ct * 16 + c] =
              f2bf((acc[qf][ct][r] + bv) * qs);
      }
    __syncthreads();
    unsigned short* outp = (mat ? Kbf : Qbf) + (size_t)rt * 128;
#pragma unroll
    for (int i = 0; i < 8; ++i) {
      const int e = i * 2048 + t * 8;
      *(ushort8*)&outp[e] = *(const ushort8*)&Xs[(e >> 7) * LP + (e & 127)];
    }
  }
#undef WSTAGE_H
#undef WFRAG_H
#undef XFRAG
}

// ---------------------------------------------------------------------------
// Stage 2: causal attention -- EXACT r12/r18 (best measured).  2-wave
// 128-thread blocks, grid 1024 (4 blocks/CU), K/V double-buffered via
// global_load_lds, prefetch issued before compute, __syncthreads drain.
// 32x32x16 MFMA, in-register P (cvt_pk + permlane32_swap), acc5 ones-MFMA
// row sums, setprio around MFMA clusters.  XCD-chunked, heavy tiles first.
// ---------------------------------------------------------------------------
__global__ __launch_bounds__(128, 2) void attn_kernel(
    const unsigned short* __restrict__ Qbf, const unsigned short* __restrict__ Kbf,
    const unsigned short* __restrict__ Vt, const float* __restrict__ Vmean,
    const int* __restrict__ time_mask, float* __restrict__ out)
{
  __shared__ __align__(16) char smem[33280];  // K dbuf 16K | V dbuf 16K | tmx

  const int tid = threadIdx.x;
  const int lane = tid & 63, w = tid >> 6;    // w in {0,1}
  const int lq = lane & 31, hi = lane >> 5;
  const int s7 = lq & 7;

  const int wgid = blockIdx.x;
  const int xcd = wgid & 7;
  const int idx = wgid >> 3;                  // 0..127
  const int bh  = xcd * 8 + (idx & 7);        // 8 bh per XCD
  const int qt  = 15 - (idx >> 3);            // heavy q-tiles first
  const int qbase = qt * 64;
  const int b = bh >> 1, h = bh & 1;

  const unsigned short* Qp = Qbf + ((size_t)b * LSEQ) * 128 + h * 64;
  const char* Kpb = (const char*)(Kbf + ((size_t)b * LSEQ) * 128 + h * 64);
  const char* Vpb = (const char*)(Vt + (size_t)bh * (DH * LSEQ));

  const int nkv = qt + 1;

#define STAGE(tkv, bi) do {                                                   \
    const int kv_ = (tkv) * 64;                                               \
    _Pragma("unroll")                                                         \
    for (int r_ = 0; r_ < 4; ++r_) {                                          \
      const int off_ = tid * 16 + r_ * 2048;                                  \
      const int row_ = off_ >> 7;                                             \
      const int chk_ = (((off_ >> 4) & 7) ^ (row_ & 7)) << 4;                 \
      gload16(Kpb + (size_t)(kv_ + row_) * 256 + chk_,                        \
              (char*)smem + (bi) * 8192 + r_ * 2048 + tid * 16);              \
      gload16(Vpb + (size_t)row_ * 2048 + kv_ * 2 + chk_,                     \
              (char*)smem + 16384 + (bi) * 8192 + r_ * 2048 + tid * 16);      \
    }                                                                         \
  } while (0)

#define PLSWAP(x_, y_) asm("v_permlane32_swap_b32 %0, %1" : "+v"(x_), "+v"(y_))

#define MKPA(pk_, m_, dst_) do {                                              \
    unsigned x0_ = pk_[4*(m_)], x1_ = pk_[4*(m_)+1];                          \
    unsigned y0_ = pk_[4*(m_)+2], y1_ = pk_[4*(m_)+3];                        \
    PLSWAP(x0_, y0_); PLSWAP(x1_, y1_);                                       \
    u32x4 u_ = {x0_, x1_, y0_, y1_};                                          \
    dst_ = *(bf16x8*)&u_;                                                     \
  } while (0)

  bf16x8 qa[4];
#pragma unroll
  for (int kc4 = 0; kc4 < 4; ++kc4)
    qa[kc4] = *(const bf16x8*)&Qp[(qbase + w * 32 + lq) * 128 + kc4 * 16 + hi * 8];

  const __bf16 one = (__bf16)1.0f;
  const bf16x8 vones = {one, one, one, one, one, one, one, one};

  f32x16 acc0 = {}, acc1 = {}, acc5 = {};

  STAGE(0, 0);
  __syncthreads();

  for (int tk = 0; tk < nkv; ++tk) {
    const int cur = tk & 1;
    if (tk + 1 < nkv) STAGE(tk + 1, cur ^ 1);

    const char* Kl = smem + cur * 8192;
    const char* Vl = smem + 16384 + cur * 8192;

    f32x16 s0 = {}, s1 = {};
    __builtin_amdgcn_s_setprio(1);
#pragma unroll
    for (int kc4 = 0; kc4 < 4; ++kc4) {
      const bf16x8 kf = *(const bf16x8*)(Kl + (lq << 7) + (((2 * kc4 + hi) ^ s7) << 4));
      s0 = __builtin_amdgcn_mfma_f32_32x32x16_bf16(kf, qa[kc4], s0, 0, 0, 0);
    }
#pragma unroll
    for (int kc4 = 0; kc4 < 4; ++kc4) {
      const bf16x8 kf = *(const bf16x8*)(Kl + ((32 + lq) << 7) + (((2 * kc4 + hi) ^ s7) << 4));
      s1 = __builtin_amdgcn_mfma_f32_32x32x16_bf16(kf, qa[kc4], s1, 0, 0, 0);
    }
    __builtin_amdgcn_s_setprio(0);

    bf16x8 vf[4][2];
#pragma unroll
    for (int kc4 = 0; kc4 < 4; ++kc4)
#pragma unroll
      for (int dt = 0; dt < 2; ++dt)
        vf[kc4][dt] = *(const bf16x8*)(Vl + ((dt * 32 + lq) << 7) + (((2 * kc4 + hi) ^ s7) << 4));

    const bool diag = (tk == nkv - 1);
    const int kv = tk * 64;
    const int qrow = qbase + w * 32 + lq;
    float p0[16], p1[16];
#pragma unroll
    for (int r = 0; r < 16; ++r) {
      const int krow = (r & 3) + 8 * (r >> 2) + 4 * hi;
      float e0 = __builtin_amdgcn_exp2f(s0[r]);
      float e1 = __builtin_amdgcn_exp2f(s1[r]);
      if (diag) {
        if (kv + krow > qrow)      e0 = 0.f;
        if (kv + 32 + krow > qrow) e1 = 0.f;
      }
      p0[r] = e0; p1[r] = e1;
    }

    unsigned pk0[8], pk1[8];
#pragma unroll
    for (int bb = 0; bb < 4; ++bb) {
      pk0[2*bb]   = cvt_pk_bf16(p0[4*bb],   p0[4*bb+1]);
      pk0[2*bb+1] = cvt_pk_bf16(p0[4*bb+2], p0[4*bb+3]);
      pk1[2*bb]   = cvt_pk_bf16(p1[4*bb],   p1[4*bb+1]);
      pk1[2*bb+1] = cvt_pk_bf16(p1[4*bb+2], p1[4*bb+3]);
    }

    bf16x8 pa;
    __builtin_amdgcn_s_setprio(1);
    MKPA(pk0, 0, pa);
    acc0 = __builtin_amdgcn_mfma_f32_32x32x16_bf16(pa, vf[0][0], acc0, 0, 0, 0);
    acc1 = __builtin_amdgcn_mfma_f32_32x32x16_bf16(pa, vf[0][1], acc1, 0, 0, 0);
    acc5 = __builtin_amdgcn_mfma_f32_32x32x16_bf16(pa, vones,    acc5, 0, 0, 0);
    MKPA(pk0, 1, pa);
    acc0 = __builtin_amdgcn_mfma_f32_32x32x16_bf16(pa, vf[1][0], acc0, 0, 0, 0);
    acc1 = __builtin_amdgcn_mfma_f32_32x32x16_bf16(pa, vf[1][1], acc1, 0, 0, 0);
    acc5 = __builtin_amdgcn_mfma_f32_32x32x16_bf16(pa, vones,    acc5, 0, 0, 0);
    MKPA(pk1, 0, pa);
    acc0 = __builtin_amdgcn_mfma_f32_32x32x16_bf16(pa, vf[2][0], acc0, 0, 0, 0);
    acc1 = __builtin_amdgcn_mfma_f32_32x32x16_bf16(pa, vf[2][1], acc1, 0, 0, 0);
    acc5 = __builtin_amdgcn_mfma_f32_32x32x16_bf16(pa, vones,    acc5, 0, 0, 0);
    MKPA(pk1, 1, pa);
    acc0 = __builtin_amdgcn_mfma_f32_32x32x16_bf16(pa, vf[3][0], acc0, 0, 0, 0);
    acc1 = __builtin_amdgcn_mfma_f32_32x32x16_bf16(pa, vf[3][1], acc1, 0, 0, 0);
    acc5 = __builtin_amdgcn_mfma_f32_32x32x16_bf16(pa, vones,    acc5, 0, 0, 0);
    __builtin_amdgcn_s_setprio(0);

    __syncthreads();
  }

  // ---- epilogue: acc5[r] holds the row sum in the output layout ----
  int* tmx = (int*)(smem + 32768 + w * 128);
  if (hi == 0)
    tmx[lq] = time_mask[b * LSEQ + qbase + w * 32 + lq];
  asm volatile("s_waitcnt lgkmcnt(0)" ::: "memory");
  __builtin_amdgcn_sched_barrier(0);

  const float vmv0 = Vmean[bh * DH + lq]      * (1.0f / 1024.0f);
  const float vmv1 = Vmean[bh * DH + 32 + lq] * (1.0f / 1024.0f);

#pragma unroll
  for (int r = 0; r < 16; ++r) {
    const int qr = (r & 3) + 8 * (r >> 2) + 4 * hi;
    const int tm = tmx[qr];
    const float wv = 1.0f / acc5[r];
    float* orow = out + (size_t)(b * LSEQ + qbase + w * 32 + qr) * (NH * DH) + h * DH;
    orow[lq]      = tm ? vmv0 : acc0[r] * wv;
    orow[32 + lq] = tm ? vmv1 : acc1[r] * wv;
  }
#undef STAGE
#undef PLSWAP
#undef MKPA
}

// ---------------------------------------------------------------------------
extern "C" void kernel_launch(void* const* d_in, const int* in_sizes, int n_in,
                              void* d_out, int out_size, void* d_ws, size_t ws_size,
                              hipStream_t stream) {
  const float* queries   = (const float*)d_in[0];
  const float* keys      = (const float*)d_in[1];
  const int*   time_mask = (const int*)d_in[2];
  // d_in[3] = attn_mask: deterministically triu(k=1); computed from indices.
  const float* Qw = (const float*)d_in[4];
  const float* Qb = (const float*)d_in[5];
  const float* Kw = (const float*)d_in[6];
  const float* Kb = (const float*)d_in[7];
  const float* Vw = (const float*)d_in[8];
  const float* Vb = (const float*)d_in[9];
  float* out = (float*)d_out;

  char* ws = (char*)d_ws;
  unsigned short* Wbf   = (unsigned short*)(ws);                      //  98,304 B
  float*          Vmean = (float*)(ws + 98304);                       //  16,384 B
  unsigned short* Qbf   = (unsigned short*)(ws + 114688);             // 8,388,608
  unsigned short* Kbf   = (unsigned short*)(ws + 8503296);            // 8,388,608
  unsigned short* Vtp   = (unsigned short*)(ws + 16891904);           // 8,388,608

  wconv_kernel<<<48, 256, 0, stream>>>(Qw, Kw, Vw, Wbf, Vmean);
  proj_kernel<<<768, 256, 0, stream>>>(queries, keys, Wbf, Qb, Kb, Vb,
                                       Qbf, Kbf, Vtp, Vmean);
  attn_kernel<<<1024, 128, 0, stream>>>(Qbf, Kbf, Vtp, Vmean, time_mask, out);
}